// Round 4
// baseline (930.325 us; speedup 1.0000x reference)
//
#include <hip/hip_runtime.h>
#include <hip/hip_bf16.h>
#include <cstdint>

// Encoder_Decoder: C=80 classes, H=128, N=sum(lengths)=20640, L_max=416.
// Phases (all dense GEMMs f16 MFMA, fp32 accumulate):
//  1) concat extras (f16) into allf16[:,128:224]
//  2) allf16[:,:128] = relu(acbf @ appear_W^T + ab)      MFMA K=1024
//  3) dec16 = relu(allf16 @ feat_W^T + fb)               MFMA K=224
//  4) xp16[d][start+t] = dec16[gather] @ Wih^T + bih     MFMA K=128, per class
//  5) GRU scan: ONE WAVE per (class,dir), sync-free/LDS-free. Lane l owns
//     positions {l, l+64} (6 gate rows); h packed as half2 in 1 VGPR/lane;
//     broadcast via v_readlane; weights pre-interleaved (W[r][i],W[r][i+64]).
//     v4: weights live in 384 NAMED half2 registers (macro-generated) —
//     arrays went to scratch in v3 (rule #20), named scalars cannot.
//  6) out[n] = sigmoid(dot(outY[n,:256], out_W) + out_b)

typedef _Float16 half2_t __attribute__((ext_vector_type(2)));
typedef _Float16 half8_t __attribute__((ext_vector_type(8)));
typedef float f32x4 __attribute__((ext_vector_type(4)));

// LDS-only barrier: __syncthreads() drains vmcnt (in-flight global ops);
// cross-thread data here flows only through LDS, lgkmcnt(0) suffices.
__device__ __forceinline__ void lds_barrier() {
    asm volatile("s_waitcnt lgkmcnt(0)\n\ts_barrier" ::: "memory");
}

__device__ __forceinline__ half8_t cvt8(float4 f0, float4 f1) {
    return half8_t{(_Float16)f0.x, (_Float16)f0.y, (_Float16)f0.z, (_Float16)f0.w,
                   (_Float16)f1.x, (_Float16)f1.y, (_Float16)f1.z, (_Float16)f1.w};
}

// ---------------- 1. concat extras (f16) ----------------
__global__ __launch_bounds__(256) void concat_kernel(
    const float* __restrict__ score, const float* __restrict__ box,
    const float* __restrict__ orig, _Float16* __restrict__ allf, int N)
{
    int idx = blockIdx.x * 256 + threadIdx.x;
    int total = N * 96;
    if (idx >= total) return;
    int n = idx / 96, j = idx - n * 96;
    float v;
    if (j < 32)      v = score[(size_t)n * 32 + j];
    else if (j < 64) v = box  [(size_t)n * 32 + j - 32];
    else             v = orig [(size_t)n * 32 + j - 64];
    allf[(size_t)n * 224 + 128 + j] = (_Float16)v;
}

// ---------------- MFMA GEMM: C(N x 128) = act(A(N x K) @ B(128 x K)^T + bias) ----------------
// 256 thr = 4 waves; tile 64 rows x 128 cols; wave = 1 row-tile(16) x 8 col-tiles.
// K-chunk 32. LDS staged in MFMA fragment order (lane-contiguous 16B slots):
//   A slot u = rt*64 + q*16 + m  <- A[n0+rt*16+m][kc*32 + q*8 .. +7]
//   B slot u = ct*64 + q*16 + n  <- B[ct*16+n]  [kc*32 + q*8 .. +7]
// Frag layouts (m89-verified): A/B lane = idx&15 + 16*(k/8); C/D col=lane&15,
// row = 4*(lane>>4) + reg.
template<bool A_F16>
__global__ __launch_bounds__(256) void mfma_gemm_kernel(
    const void* __restrict__ Av, int lda,
    const float* __restrict__ B, int ldb,       // 128 x ldb f32 (ldb >= K)
    const float* __restrict__ bias,
    _Float16* __restrict__ Cc, int ldc,
    int Nrows, int K, int do_relu)
{
    __shared__ __align__(16) _Float16 Asl[256 * 8];   // 4 KB
    __shared__ __align__(16) _Float16 Bsl[512 * 8];   // 8 KB
    const int tid = threadIdx.x;
    const int wave = tid >> 6, lane = tid & 63;
    const int n0 = blockIdx.x * 64;

    // A staging: slot = tid
    const int a_rt = tid >> 6, a_q = (tid >> 4) & 3, a_m = tid & 15;
    int arow = n0 + a_rt * 16 + a_m; if (arow > Nrows - 1) arow = Nrows - 1;
    // B staging: slots tid and tid+256
    const int b_q = (tid >> 4) & 3, b_n = tid & 15;
    const int bcol0 = (tid >> 6) * 16 + b_n;          // ct 0..3
    const int bcol1 = bcol0 + 64;                     // ct 4..7

    f32x4 acc[8] = {};
    half8_t a_st, b_st0, b_st1;

    auto load_chunk = [&](int kc) {
        int k = kc * 32;
        if constexpr (A_F16) {
            const _Float16* A = (const _Float16*)Av;
            a_st = *(const half8_t*)(A + (size_t)arow * lda + k + a_q * 8);
        } else {
            const float* A = (const float*)Av;
            const float4* p = (const float4*)(A + (size_t)arow * lda + k + a_q * 8);
            a_st = cvt8(p[0], p[1]);
        }
        const float4* p0 = (const float4*)(B + (size_t)bcol0 * ldb + k + b_q * 8);
        const float4* p1 = (const float4*)(B + (size_t)bcol1 * ldb + k + b_q * 8);
        b_st0 = cvt8(p0[0], p0[1]);
        b_st1 = cvt8(p1[0], p1[1]);
    };

    load_chunk(0);
    const int nkc = K >> 5;
    for (int kc = 0; kc < nkc; kc++) {
        lds_barrier();                       // prev compute's LDS reads done
        *(half8_t*)(Asl + tid * 8) = a_st;
        *(half8_t*)(Bsl + tid * 8) = b_st0;
        *(half8_t*)(Bsl + (tid + 256) * 8) = b_st1;
        lds_barrier();
        if (kc + 1 < nkc) load_chunk(kc + 1);   // prefetch under MFMA
        half8_t af = *(const half8_t*)(Asl + (wave * 64 + lane) * 8);
        #pragma unroll
        for (int ct = 0; ct < 8; ct++) {
            half8_t bf = *(const half8_t*)(Bsl + (ct * 64 + lane) * 8);
            acc[ct] = __builtin_amdgcn_mfma_f32_16x16x32_f16(af, bf, acc[ct], 0, 0, 0);
        }
    }

    const int crow = n0 + wave * 16 + (lane >> 4) * 4;
    const int ccol = lane & 15;
    #pragma unroll
    for (int ct = 0; ct < 8; ct++) {
        int col = ct * 16 + ccol;
        float bv = bias[col];
        #pragma unroll
        for (int reg = 0; reg < 4; reg++) {
            int row = crow + reg;
            if (row >= Nrows) continue;
            float v = acc[ct][reg] + bv;
            if (do_relu) v = v > 0.f ? v : 0.f;
            Cc[(size_t)row * ldc + col] = (_Float16)v;
        }
    }
}

// ---------------- 4. Xp per-class MFMA GEMM (K=128) with direction gather ----------------
__global__ __launch_bounds__(256) void mfma_xp_kernel(
    const _Float16* __restrict__ dec, // N x 128 f16
    const float* __restrict__ Wih,    // C x 2 x 384 x 128 f32
    const float* __restrict__ bih,    // C x 2 x 384 f32
    const int* __restrict__ ucl,
    _Float16* __restrict__ xp,        // 2 x N x 384 f16
    int N)
{
    const int c = blockIdx.x;
    const int tile = blockIdx.y;
    const int d = blockIdx.z / 3, mt = blockIdx.z % 3;
    const int start = ucl[c];
    const int len = ucl[c + 1] - start;
    const int t0 = tile * 64;
    if (t0 >= len) return;

    __shared__ __align__(16) _Float16 Asl[256 * 8];
    __shared__ __align__(16) _Float16 Bsl[512 * 8];
    const int tid = threadIdx.x;
    const int wave = tid >> 6, lane = tid & 63;

    const int a_rt = tid >> 6, a_q = (tid >> 4) & 3, a_m = tid & 15;
    int t = t0 + a_rt * 16 + a_m; if (t > len - 1) t = len - 1;
    const int srow = start + (d ? (len - 1 - t) : t);

    const float* Bb = Wih + ((size_t)(c * 2 + d) * 384 + mt * 128) * 128;
    const int b_q = (tid >> 4) & 3, b_n = tid & 15;
    const int bcol0 = (tid >> 6) * 16 + b_n;
    const int bcol1 = bcol0 + 64;

    f32x4 acc[8] = {};
    half8_t a_st, b_st0, b_st1;

    auto load_chunk = [&](int kc) {
        int k = kc * 32;
        a_st = *(const half8_t*)(dec + (size_t)srow * 128 + k + a_q * 8);
        const float4* p0 = (const float4*)(Bb + (size_t)bcol0 * 128 + k + b_q * 8);
        const float4* p1 = (const float4*)(Bb + (size_t)bcol1 * 128 + k + b_q * 8);
        b_st0 = cvt8(p0[0], p0[1]);
        b_st1 = cvt8(p1[0], p1[1]);
    };

    load_chunk(0);
    for (int kc = 0; kc < 4; kc++) {
        lds_barrier();
        *(half8_t*)(Asl + tid * 8) = a_st;
        *(half8_t*)(Bsl + tid * 8) = b_st0;
        *(half8_t*)(Bsl + (tid + 256) * 8) = b_st1;
        lds_barrier();
        if (kc + 1 < 4) load_chunk(kc + 1);
        half8_t af = *(const half8_t*)(Asl + (wave * 64 + lane) * 8);
        #pragma unroll
        for (int ct = 0; ct < 8; ct++) {
            half8_t bf = *(const half8_t*)(Bsl + (ct * 64 + lane) * 8);
            acc[ct] = __builtin_amdgcn_mfma_f32_16x16x32_f16(af, bf, acc[ct], 0, 0, 0);
        }
    }

    const float* bias = bih + (size_t)(c * 2 + d) * 384 + mt * 128;
    const int trow = t0 + wave * 16 + (lane >> 4) * 4;
    const int ccol = lane & 15;
    #pragma unroll
    for (int ct = 0; ct < 8; ct++) {
        int col = ct * 16 + ccol;
        float bv = bias[col];
        #pragma unroll
        for (int reg = 0; reg < 4; reg++) {
            int tt = trow + reg;
            if (tt >= len) continue;
            float v = acc[ct][reg] + bv;
            xp[((size_t)d * N + start + tt) * 384 + mt * 128 + col] = (_Float16)v;
        }
    }
}

// ---------------- 5. GRU scan: one wave per (class,dir), sync-free ----------------
// Lane l owns positions p=l and p=l+64. Gate rows per lane:
//   pos A=l:    r=row l,     z=row l+128, n=row l+256
//   pos B=l+64: r=row l+64,  z=row l+192, n=row l+320
// h lives as one packed half2 VGPR per lane: (h[l], h[l+64]).
// Weight element i (0..63) of a row: (W[row][i], W[row][i+64]) so that
// dot2(w_i, readlane(h2, i)) = W[row][i]*h[i] + W[row][i+64]*h[i+64].
// All 384 weights are NAMED registers w{R0,Z0,N0,R1,Z1,N1}_{q}_{j}, q=0..15,
// j=0..3 (element i = 4q+j) — static access only, cannot go to scratch.
#define RPT16(M) M(0) M(1) M(2) M(3) M(4) M(5) M(6) M(7) \
                 M(8) M(9) M(10) M(11) M(12) M(13) M(14) M(15)

#define DECL1(P, q) half2_t P##_##q##_0, P##_##q##_1, P##_##q##_2, P##_##q##_3;
#define DECLQ(q) DECL1(wR0, q) DECL1(wZ0, q) DECL1(wN0, q) \
                 DECL1(wR1, q) DECL1(wZ1, q) DECL1(wN1, q)

// row is 128 f32 = 32 float4; element pair (i, i+64) = float4 idx (q, q+16)
#define LOAD1(P, ptr, q)                                                      \
    {                                                                         \
        float4 fa = ((const float4*)(ptr))[q];                                \
        float4 fb = ((const float4*)(ptr))[(q) + 16];                         \
        P##_##q##_0 = half2_t{(_Float16)fa.x, (_Float16)fb.x};                \
        P##_##q##_1 = half2_t{(_Float16)fa.y, (_Float16)fb.y};                \
        P##_##q##_2 = half2_t{(_Float16)fa.z, (_Float16)fb.z};                \
        P##_##q##_3 = half2_t{(_Float16)fa.w, (_Float16)fb.w};                \
    }
#define LOADQ(q) LOAD1(wR0, pR0, q) LOAD1(wZ0, pZ0, q) LOAD1(wN0, pN0, q) \
                 LOAD1(wR1, pR1, q) LOAD1(wZ1, pZ1, q) LOAD1(wN1, pN1, q)

#define DOT1(q, j)                                                            \
    {                                                                         \
        int hb = __builtin_amdgcn_readlane(hvi, 4 * (q) + (j));               \
        half2_t h2 = __builtin_bit_cast(half2_t, hb);                         \
        aR0 = __builtin_amdgcn_fdot2(wR0_##q##_##j, h2, aR0, false);          \
        aZ0 = __builtin_amdgcn_fdot2(wZ0_##q##_##j, h2, aZ0, false);          \
        aN0 = __builtin_amdgcn_fdot2(wN0_##q##_##j, h2, aN0, false);          \
        aR1 = __builtin_amdgcn_fdot2(wR1_##q##_##j, h2, aR1, false);          \
        aZ1 = __builtin_amdgcn_fdot2(wZ1_##q##_##j, h2, aZ1, false);          \
        aN1 = __builtin_amdgcn_fdot2(wN1_##q##_##j, h2, aN1, false);          \
    }
#define DOTQ(q) DOT1(q, 0) DOT1(q, 1) DOT1(q, 2) DOT1(q, 3)

__global__ __launch_bounds__(64, 1) void gru_kernel(
    const _Float16* __restrict__ xp,  // 2 x N x 384 f16
    const float* __restrict__ Whh,    // C x 2 x 384 x 128
    const float* __restrict__ bhh,    // C x 2 x 384
    const int* __restrict__ ucl,
    float* __restrict__ outY,         // N x 256 f32
    int N)
{
    const int c = blockIdx.x, d = blockIdx.y;
    const int start = ucl[c];
    const int len = ucl[c + 1] - start;
    const int l = threadIdx.x;        // 0..63

    const float* wbase = Whh + (size_t)(c * 2 + d) * 384 * 128;
    const float* pR0 = wbase + (size_t)l * 128;
    const float* pZ0 = wbase + (size_t)(l + 128) * 128;
    const float* pN0 = wbase + (size_t)(l + 256) * 128;
    const float* pR1 = wbase + (size_t)(l + 64) * 128;
    const float* pZ1 = wbase + (size_t)(l + 192) * 128;
    const float* pN1 = wbase + (size_t)(l + 320) * 128;

    RPT16(DECLQ)
    RPT16(LOADQ)

    const float* bb = bhh + (size_t)(c * 2 + d) * 384;
    const float bR0 = bb[l],      bZ0 = bb[l + 128], bN0 = bb[l + 256];
    const float bR1 = bb[l + 64], bZ1 = bb[l + 192], bN1 = bb[l + 320];

    const _Float16* xpb = xp + ((size_t)d * N + start) * 384;
    float* outb = outY + (size_t)start * 256 + d * 128;

    // current-step x in registers; next step prefetched each iteration
    float xr0 = (float)xpb[l],      xz0 = (float)xpb[128 + l], xn0 = (float)xpb[256 + l];
    float xr1 = (float)xpb[64 + l], xz1 = (float)xpb[192 + l], xn1 = (float)xpb[320 + l];

    float hA = 0.f, hB = 0.f;
    int hvi = 0;                      // bits of packed half2 (hA, hB)

    for (int t = 0; t < len; t++) {
        // prefetch next step's x (L2/L3-resident; full-substep cover)
        int tn = (t + 1 < len) ? (t + 1) : t;
        const _Float16* xt = xpb + (size_t)tn * 384;
        float pr0 = (float)xt[l],      pz0 = (float)xt[128 + l], pn0 = (float)xt[256 + l];
        float pr1 = (float)xt[64 + l], pz1 = (float)xt[192 + l], pn1 = (float)xt[320 + l];

        float aR0 = bR0, aZ0 = bZ0, aN0 = bN0;
        float aR1 = bR1, aZ1 = bZ1, aN1 = bN1;
        RPT16(DOTQ)

        // two independent activation chains (ILP for the transcendental tail)
        float rA = __fdividef(1.f, 1.f + __expf(-(xr0 + aR0)));
        float zA = __fdividef(1.f, 1.f + __expf(-(xz0 + aZ0)));
        float preA = xn0 + rA * aN0;
        float nA = 1.f - __fdividef(2.f, __expf(2.f * preA) + 1.f);
        float hnA = (1.f - zA) * nA + zA * hA;

        float rB = __fdividef(1.f, 1.f + __expf(-(xr1 + aR1)));
        float zB = __fdividef(1.f, 1.f + __expf(-(xz1 + aZ1)));
        float preB = xn1 + rB * aN1;
        float nB = 1.f - __fdividef(2.f, __expf(2.f * preB) + 1.f);
        float hnB = (1.f - zB) * nB + zB * hB;

        hA = hnA; hB = hnB;
        half2_t hh{(_Float16)hA, (_Float16)hB};
        hvi = __builtin_bit_cast(int, hh);

        int tt = d ? (len - 1 - t) : t;
        outb[(size_t)tt * 256 + l] = hA;
        outb[(size_t)tt * 256 + 64 + l] = hB;

        xr0 = pr0; xz0 = pz0; xn0 = pn0;
        xr1 = pr1; xz1 = pz1; xn1 = pn1;
    }
}

// ---------------- 6. head: sigmoid(dot(outY[n], out_W) + b) ----------------
__global__ __launch_bounds__(256) void final_kernel(
    const float* __restrict__ outY,   // N x 256
    const float* __restrict__ outW,   // 256
    const float* __restrict__ outb,   // 1
    float* __restrict__ out, int N)
{
    __shared__ __align__(16) float wsh[256];
    wsh[threadIdx.x] = outW[threadIdx.x];
    __syncthreads();
    const int lane = threadIdx.x & 63;
    const int wave = (blockIdx.x * 256 + threadIdx.x) >> 6;
    const int nw = gridDim.x * 4;
    float4 w4 = *(const float4*)&wsh[lane * 4];
    float b = outb[0];
    for (int n = wave; n < N; n += nw) {
        float4 y = *(const float4*)(outY + (size_t)n * 256 + lane * 4);
        float p = y.x * w4.x + y.y * w4.y + y.z * w4.z + y.w * w4.w;
        #pragma unroll
        for (int off = 32; off > 0; off >>= 1) p += __shfl_down(p, off);
        if (lane == 0) out[n] = 1.f / (1.f + __expf(-(p + b)));
    }
}

extern "C" void kernel_launch(void* const* d_in, const int* in_sizes, int n_in,
                              void* d_out, int out_size, void* d_ws, size_t ws_size,
                              hipStream_t stream)
{
    const float* acbf  = (const float*)d_in[3];
    const float* score = (const float*)d_in[4];
    const float* box   = (const float*)d_in[5];
    const float* orig  = (const float*)d_in[6];
    const int*   ucl   = (const int*)d_in[8];
    const float* aW  = (const float*)d_in[9];
    const float* ab  = (const float*)d_in[10];
    const float* fW  = (const float*)d_in[11];
    const float* fb  = (const float*)d_in[12];
    const float* Wih = (const float*)d_in[13];
    const float* Whh = (const float*)d_in[14];
    const float* bih = (const float*)d_in[15];
    const float* bhh = (const float*)d_in[16];
    const float* oW  = (const float*)d_in[17];
    const float* ob  = (const float*)d_in[18];
    float* out = (float*)d_out;

    const int N = in_sizes[3] / 1024;   // 20640
    const int C = in_sizes[7];          // 80

    // workspace: allf16 N*224 | dec16 N*128 | xp16 2*N*384 | outY f32 N*256  (~67 MB)
    _Float16* allf16 = (_Float16*)d_ws;
    _Float16* dec16  = allf16 + (size_t)N * 224;
    _Float16* xp16   = dec16 + (size_t)N * 128;
    float*    outY   = (float*)(xp16 + (size_t)2 * N * 384);

    dim3 blk(256);
    const int rowblocks = (N + 63) / 64;
    concat_kernel<<<dim3((N * 96 + 255) / 256), blk, 0, stream>>>(score, box, orig, allf16, N);
    mfma_gemm_kernel<false><<<dim3(rowblocks), blk, 0, stream>>>(
        (const void*)acbf, 1024, aW, 1024, ab, allf16, 224, N, 1024, 1);
    mfma_gemm_kernel<true><<<dim3(rowblocks), blk, 0, stream>>>(
        (const void*)allf16, 224, fW, 224, fb, dec16, 128, N, 224, 1);
    mfma_xp_kernel<<<dim3(C, 7, 6), blk, 0, stream>>>(dec16, Wih, bih, ucl, xp16, N);
    gru_kernel<<<dim3(C, 2), dim3(64), 0, stream>>>(xp16, Whh, bhh, ucl, outY, N);
    final_kernel<<<dim3(160), blk, 0, stream>>>(outY, oW, ob, out, N);
}

// Round 5
// 628.900 us; speedup vs baseline: 1.4793x; 1.4793x over previous
//
#include <hip/hip_runtime.h>
#include <hip/hip_bf16.h>
#include <cstdint>

// Encoder_Decoder: C=80 classes, H=128, N=sum(lengths)=20640, L_max=416.
// Phases (all dense GEMMs f16 MFMA, fp32 accumulate):
//  1) concat extras (f16) into allf16[:,128:224]
//  2) allf16[:,:128] = relu(acbf @ appear_W^T + ab)      MFMA K=1024
//  3) dec16 = relu(allf16 @ feat_W^T + fb)               MFMA K=224
//  4) xp16[d][start+t] = dec16[gather] @ Wih^T + bih     MFMA K=128, per class
//  5) GRU scan: 128 thr (2 waves) per (class,dir); thread g owns rows
//     {g,g+128,g+256} (192 weight VGPRs — fits the 256 arch-VGPR cap that
//     killed the 1-wave/384-reg variant). h broadcast: ONE ds_read_b32/lane
//     (pair h[2l],h[2l+1]) + 64 v_readlane -> SGPR-operand v_dot2. Only 2
//     LDS ops on the serial chain per substep (1 write, 1 read).
//  6) out[n] = sigmoid(dot(outY[n,:256], out_W) + out_b)

typedef _Float16 half2_t __attribute__((ext_vector_type(2)));
typedef _Float16 half8_t __attribute__((ext_vector_type(8)));
typedef float f32x4 __attribute__((ext_vector_type(4)));

// LDS-only barrier: __syncthreads() drains vmcnt (in-flight global ops);
// cross-thread data here flows only through LDS, lgkmcnt(0) suffices.
__device__ __forceinline__ void lds_barrier() {
    asm volatile("s_waitcnt lgkmcnt(0)\n\ts_barrier" ::: "memory");
}

__device__ __forceinline__ half8_t cvt8(float4 f0, float4 f1) {
    return half8_t{(_Float16)f0.x, (_Float16)f0.y, (_Float16)f0.z, (_Float16)f0.w,
                   (_Float16)f1.x, (_Float16)f1.y, (_Float16)f1.z, (_Float16)f1.w};
}

// ---------------- 1. concat extras (f16) ----------------
__global__ __launch_bounds__(256) void concat_kernel(
    const float* __restrict__ score, const float* __restrict__ box,
    const float* __restrict__ orig, _Float16* __restrict__ allf, int N)
{
    int idx = blockIdx.x * 256 + threadIdx.x;
    int total = N * 96;
    if (idx >= total) return;
    int n = idx / 96, j = idx - n * 96;
    float v;
    if (j < 32)      v = score[(size_t)n * 32 + j];
    else if (j < 64) v = box  [(size_t)n * 32 + j - 32];
    else             v = orig [(size_t)n * 32 + j - 64];
    allf[(size_t)n * 224 + 128 + j] = (_Float16)v;
}

// ---------------- MFMA GEMM: C(N x 128) = act(A(N x K) @ B(128 x K)^T + bias) ----------------
// 256 thr = 4 waves; tile 64 rows x 128 cols; wave = 1 row-tile(16) x 8 col-tiles.
// K-chunk 32. LDS staged in MFMA fragment order (lane-contiguous 16B slots):
//   A slot u = rt*64 + q*16 + m  <- A[n0+rt*16+m][kc*32 + q*8 .. +7]
//   B slot u = ct*64 + q*16 + n  <- B[ct*16+n]  [kc*32 + q*8 .. +7]
// Frag layouts (m89-verified): A/B lane = idx&15 + 16*(k/8); C/D col=lane&15,
// row = 4*(lane>>4) + reg.
template<bool A_F16>
__global__ __launch_bounds__(256) void mfma_gemm_kernel(
    const void* __restrict__ Av, int lda,
    const float* __restrict__ B, int ldb,       // 128 x ldb f32 (ldb >= K)
    const float* __restrict__ bias,
    _Float16* __restrict__ Cc, int ldc,
    int Nrows, int K, int do_relu)
{
    __shared__ __align__(16) _Float16 Asl[256 * 8];   // 4 KB
    __shared__ __align__(16) _Float16 Bsl[512 * 8];   // 8 KB
    const int tid = threadIdx.x;
    const int wave = tid >> 6, lane = tid & 63;
    const int n0 = blockIdx.x * 64;

    // A staging: slot = tid
    const int a_rt = tid >> 6, a_q = (tid >> 4) & 3, a_m = tid & 15;
    int arow = n0 + a_rt * 16 + a_m; if (arow > Nrows - 1) arow = Nrows - 1;
    // B staging: slots tid and tid+256
    const int b_q = (tid >> 4) & 3, b_n = tid & 15;
    const int bcol0 = (tid >> 6) * 16 + b_n;          // ct 0..3
    const int bcol1 = bcol0 + 64;                     // ct 4..7

    f32x4 acc[8] = {};
    half8_t a_st, b_st0, b_st1;

    auto load_chunk = [&](int kc) {
        int k = kc * 32;
        if constexpr (A_F16) {
            const _Float16* A = (const _Float16*)Av;
            a_st = *(const half8_t*)(A + (size_t)arow * lda + k + a_q * 8);
        } else {
            const float* A = (const float*)Av;
            const float4* p = (const float4*)(A + (size_t)arow * lda + k + a_q * 8);
            a_st = cvt8(p[0], p[1]);
        }
        const float4* p0 = (const float4*)(B + (size_t)bcol0 * ldb + k + b_q * 8);
        const float4* p1 = (const float4*)(B + (size_t)bcol1 * ldb + k + b_q * 8);
        b_st0 = cvt8(p0[0], p0[1]);
        b_st1 = cvt8(p1[0], p1[1]);
    };

    load_chunk(0);
    const int nkc = K >> 5;
    for (int kc = 0; kc < nkc; kc++) {
        lds_barrier();                       // prev compute's LDS reads done
        *(half8_t*)(Asl + tid * 8) = a_st;
        *(half8_t*)(Bsl + tid * 8) = b_st0;
        *(half8_t*)(Bsl + (tid + 256) * 8) = b_st1;
        lds_barrier();
        if (kc + 1 < nkc) load_chunk(kc + 1);   // prefetch under MFMA
        half8_t af = *(const half8_t*)(Asl + (wave * 64 + lane) * 8);
        #pragma unroll
        for (int ct = 0; ct < 8; ct++) {
            half8_t bf = *(const half8_t*)(Bsl + (ct * 64 + lane) * 8);
            acc[ct] = __builtin_amdgcn_mfma_f32_16x16x32_f16(af, bf, acc[ct], 0, 0, 0);
        }
    }

    const int crow = n0 + wave * 16 + (lane >> 4) * 4;
    const int ccol = lane & 15;
    #pragma unroll
    for (int ct = 0; ct < 8; ct++) {
        int col = ct * 16 + ccol;
        float bv = bias[col];
        #pragma unroll
        for (int reg = 0; reg < 4; reg++) {
            int row = crow + reg;
            if (row >= Nrows) continue;
            float v = acc[ct][reg] + bv;
            if (do_relu) v = v > 0.f ? v : 0.f;
            Cc[(size_t)row * ldc + col] = (_Float16)v;
        }
    }
}

// ---------------- 4. Xp per-class MFMA GEMM (K=128) with direction gather ----------------
__global__ __launch_bounds__(256) void mfma_xp_kernel(
    const _Float16* __restrict__ dec, // N x 128 f16
    const float* __restrict__ Wih,    // C x 2 x 384 x 128 f32
    const float* __restrict__ bih,    // C x 2 x 384 f32
    const int* __restrict__ ucl,
    _Float16* __restrict__ xp,        // 2 x N x 384 f16
    int N)
{
    const int c = blockIdx.x;
    const int tile = blockIdx.y;
    const int d = blockIdx.z / 3, mt = blockIdx.z % 3;
    const int start = ucl[c];
    const int len = ucl[c + 1] - start;
    const int t0 = tile * 64;
    if (t0 >= len) return;

    __shared__ __align__(16) _Float16 Asl[256 * 8];
    __shared__ __align__(16) _Float16 Bsl[512 * 8];
    const int tid = threadIdx.x;
    const int wave = tid >> 6, lane = tid & 63;

    const int a_rt = tid >> 6, a_q = (tid >> 4) & 3, a_m = tid & 15;
    int t = t0 + a_rt * 16 + a_m; if (t > len - 1) t = len - 1;
    const int srow = start + (d ? (len - 1 - t) : t);

    const float* Bb = Wih + ((size_t)(c * 2 + d) * 384 + mt * 128) * 128;
    const int b_q = (tid >> 4) & 3, b_n = tid & 15;
    const int bcol0 = (tid >> 6) * 16 + b_n;
    const int bcol1 = bcol0 + 64;

    f32x4 acc[8] = {};
    half8_t a_st, b_st0, b_st1;

    auto load_chunk = [&](int kc) {
        int k = kc * 32;
        a_st = *(const half8_t*)(dec + (size_t)srow * 128 + k + a_q * 8);
        const float4* p0 = (const float4*)(Bb + (size_t)bcol0 * 128 + k + b_q * 8);
        const float4* p1 = (const float4*)(Bb + (size_t)bcol1 * 128 + k + b_q * 8);
        b_st0 = cvt8(p0[0], p0[1]);
        b_st1 = cvt8(p1[0], p1[1]);
    };

    load_chunk(0);
    for (int kc = 0; kc < 4; kc++) {
        lds_barrier();
        *(half8_t*)(Asl + tid * 8) = a_st;
        *(half8_t*)(Bsl + tid * 8) = b_st0;
        *(half8_t*)(Bsl + (tid + 256) * 8) = b_st1;
        lds_barrier();
        if (kc + 1 < 4) load_chunk(kc + 1);
        half8_t af = *(const half8_t*)(Asl + (wave * 64 + lane) * 8);
        #pragma unroll
        for (int ct = 0; ct < 8; ct++) {
            half8_t bf = *(const half8_t*)(Bsl + (ct * 64 + lane) * 8);
            acc[ct] = __builtin_amdgcn_mfma_f32_16x16x32_f16(af, bf, acc[ct], 0, 0, 0);
        }
    }

    const float* bias = bih + (size_t)(c * 2 + d) * 384 + mt * 128;
    const int trow = t0 + wave * 16 + (lane >> 4) * 4;
    const int ccol = lane & 15;
    #pragma unroll
    for (int ct = 0; ct < 8; ct++) {
        int col = ct * 16 + ccol;
        float bv = bias[col];
        #pragma unroll
        for (int reg = 0; reg < 4; reg++) {
            int tt = trow + reg;
            if (tt >= len) continue;
            float v = acc[ct][reg] + bv;
            xp[((size_t)d * N + start + tt) * 384 + mt * 128 + col] = (_Float16)v;
        }
    }
}

// ---------------- 5. GRU scan: 2 waves, readlane broadcast ----------------
// One block per (class,dir), 128 threads; thread g owns gate rows
// {g, g+128, g+256}. Weights: 192 half2 VGPRs/thread (consecutive-pair
// packing w[i] = (W[row][2i], W[row][2i+1])), v1-proven to fit (VGPR~196).
// Serial chain per substep: ds_read_b32 (lane l -> pair h[2l],h[2l+1])
// -> lgkmcnt(0) -> 64 readlane + 192 dot2 (6 acc chains) -> activations
// -> ds_write_b16 -> lds_barrier. Only 2 LDS ops on the chain (vs 17 in
// the b128-fragment variant); x prefetched 1 step ahead from global.
__global__ __launch_bounds__(128, 1) void gru_kernel(
    const _Float16* __restrict__ xp,  // 2 x N x 384 f16
    const float* __restrict__ Whh,    // C x 2 x 384 x 128
    const float* __restrict__ bhh,    // C x 2 x 384
    const int* __restrict__ ucl,
    float* __restrict__ outY,         // N x 256 f32
    int N)
{
    const int c = blockIdx.x, d = blockIdx.y;
    const int start = ucl[c];
    const int len = ucl[c + 1] - start;
    const int g = threadIdx.x;        // 0..127
    const int l = g & 63;             // lane

    const float* wbase = Whh + (size_t)(c * 2 + d) * 384 * 128;
    half2_t w0[64], w1[64], w2[64];
    {
        const float2* r0 = (const float2*)(wbase + (size_t)g * 128);
        const float2* r1 = (const float2*)(wbase + (size_t)(g + 128) * 128);
        const float2* r2 = (const float2*)(wbase + (size_t)(g + 256) * 128);
        #pragma unroll
        for (int i = 0; i < 64; i++) {
            float2 a = r0[i];
            w0[i] = half2_t{(_Float16)a.x, (_Float16)a.y};
        }
        #pragma unroll
        for (int i = 0; i < 64; i++) {
            float2 a = r1[i];
            w1[i] = half2_t{(_Float16)a.x, (_Float16)a.y};
        }
        #pragma unroll
        for (int i = 0; i < 64; i++) {
            float2 a = r2[i];
            w2[i] = half2_t{(_Float16)a.x, (_Float16)a.y};
        }
    }
    const float* bb = bhh + (size_t)(c * 2 + d) * 384;
    const float bh0 = bb[g], bh1 = bb[g + 128], bh2 = bb[g + 256];

    __shared__ __align__(4) _Float16 hbuf[2][128];    // 512 B double buffer
    hbuf[0][g] = (_Float16)0.f;

    const _Float16* xpb = xp + ((size_t)d * N + start) * 384;
    float* outb = outY + (size_t)start * 256 + d * 128;

    float x0 = (float)xpb[g], x1 = (float)xpb[128 + g], x2 = (float)xpb[256 + g];
    float hcur = 0.f;
    lds_barrier();

    for (int t = 0; t < len; t++) {
        // h pair for this lane: (h[2l], h[2l+1]) — one b32, conflict-free,
        // identical content in both waves.
        int hvi = ((const int*)hbuf[t & 1])[l];

        // prefetch next step's x under the dot loop (off-chain)
        int tn = (t + 1 < len) ? (t + 1) : t;
        const _Float16* xt = xpb + (size_t)tn * 384;
        float p0 = (float)xt[g], p1 = (float)xt[128 + g], p2 = (float)xt[256 + g];

        float a0 = bh0, a1 = bh1, a2 = bh2;
        float b0 = 0.f, b1 = 0.f, b2 = 0.f;
        #pragma unroll
        for (int i = 0; i < 32; i++) {
            int hbL = __builtin_amdgcn_readlane(hvi, i);
            int hbH = __builtin_amdgcn_readlane(hvi, i + 32);
            half2_t hL = __builtin_bit_cast(half2_t, hbL);
            half2_t hH = __builtin_bit_cast(half2_t, hbH);
            a0 = __builtin_amdgcn_fdot2(w0[i],      hL, a0, false);
            b0 = __builtin_amdgcn_fdot2(w0[i + 32], hH, b0, false);
            a1 = __builtin_amdgcn_fdot2(w1[i],      hL, a1, false);
            b1 = __builtin_amdgcn_fdot2(w1[i + 32], hH, b1, false);
            a2 = __builtin_amdgcn_fdot2(w2[i],      hL, a2, false);
            b2 = __builtin_amdgcn_fdot2(w2[i + 32], hH, b2, false);
        }
        a0 += b0; a1 += b1; a2 += b2;

        float r = __fdividef(1.f, 1.f + __expf(-(x0 + a0)));
        float z = __fdividef(1.f, 1.f + __expf(-(x1 + a1)));
        float pre = x2 + r * a2;
        float n = 1.f - __fdividef(2.f, __expf(2.f * pre) + 1.f);
        float hnew = (1.f - z) * n + z * hcur;

        hbuf[(t + 1) & 1][g] = (_Float16)hnew;
        hcur = hnew;

        int tt = d ? (len - 1 - t) : t;
        outb[(size_t)tt * 256 + g] = hnew;

        x0 = p0; x1 = p1; x2 = p2;
        lds_barrier();
    }
}

// ---------------- 6. head: sigmoid(dot(outY[n], out_W) + b) ----------------
__global__ __launch_bounds__(256) void final_kernel(
    const float* __restrict__ outY,   // N x 256
    const float* __restrict__ outW,   // 256
    const float* __restrict__ outb,   // 1
    float* __restrict__ out, int N)
{
    __shared__ __align__(16) float wsh[256];
    wsh[threadIdx.x] = outW[threadIdx.x];
    __syncthreads();
    const int lane = threadIdx.x & 63;
    const int wave = (blockIdx.x * 256 + threadIdx.x) >> 6;
    const int nw = gridDim.x * 4;
    float4 w4 = *(const float4*)&wsh[lane * 4];
    float b = outb[0];
    for (int n = wave; n < N; n += nw) {
        float4 y = *(const float4*)(outY + (size_t)n * 256 + lane * 4);
        float p = y.x * w4.x + y.y * w4.y + y.z * w4.z + y.w * w4.w;
        #pragma unroll
        for (int off = 32; off > 0; off >>= 1) p += __shfl_down(p, off);
        if (lane == 0) out[n] = 1.f / (1.f + __expf(-(p + b)));
    }
}

extern "C" void kernel_launch(void* const* d_in, const int* in_sizes, int n_in,
                              void* d_out, int out_size, void* d_ws, size_t ws_size,
                              hipStream_t stream)
{
    const float* acbf  = (const float*)d_in[3];
    const float* score = (const float*)d_in[4];
    const float* box   = (const float*)d_in[5];
    const float* orig  = (const float*)d_in[6];
    const int*   ucl   = (const int*)d_in[8];
    const float* aW  = (const float*)d_in[9];
    const float* ab  = (const float*)d_in[10];
    const float* fW  = (const float*)d_in[11];
    const float* fb  = (const float*)d_in[12];
    const float* Wih = (const float*)d_in[13];
    const float* Whh = (const float*)d_in[14];
    const float* bih = (const float*)d_in[15];
    const float* bhh = (const float*)d_in[16];
    const float* oW  = (const float*)d_in[17];
    const float* ob  = (const float*)d_in[18];
    float* out = (float*)d_out;

    const int N = in_sizes[3] / 1024;   // 20640
    const int C = in_sizes[7];          // 80

    // workspace: allf16 N*224 | dec16 N*128 | xp16 2*N*384 | outY f32 N*256  (~67 MB)
    _Float16* allf16 = (_Float16*)d_ws;
    _Float16* dec16  = allf16 + (size_t)N * 224;
    _Float16* xp16   = dec16 + (size_t)N * 128;
    float*    outY   = (float*)(xp16 + (size_t)2 * N * 384);

    dim3 blk(256);
    const int rowblocks = (N + 63) / 64;
    concat_kernel<<<dim3((N * 96 + 255) / 256), blk, 0, stream>>>(score, box, orig, allf16, N);
    mfma_gemm_kernel<false><<<dim3(rowblocks), blk, 0, stream>>>(
        (const void*)acbf, 1024, aW, 1024, ab, allf16, 224, N, 1024, 1);
    mfma_gemm_kernel<true><<<dim3(rowblocks), blk, 0, stream>>>(
        (const void*)allf16, 224, fW, 224, fb, dec16, 128, N, 224, 1);
    mfma_xp_kernel<<<dim3(C, 7, 6), blk, 0, stream>>>(dec16, Wih, bih, ucl, xp16, N);
    gru_kernel<<<dim3(C, 2), dim3(128), 0, stream>>>(xp16, Whh, bhh, ucl, outY, N);
    final_kernel<<<dim3(160), blk, 0, stream>>>(outY, oW, ob, out, N);
}

// Round 6
// 628.860 us; speedup vs baseline: 1.4794x; 1.0001x over previous
//
#include <hip/hip_runtime.h>
#include <hip/hip_bf16.h>
#include <cstdint>

// Encoder_Decoder: C=80 classes, H=128, N=sum(lengths)=20640, L_max=416.
// Phases (all dense GEMMs f16 MFMA, fp32 accumulate):
//  1) concat extras (f16) into allf16[:,128:224]
//  2) allf16[:,:128] = relu(acbf @ appear_W^T + ab)      MFMA K=1024
//  3) dec16 = relu(allf16 @ feat_W^T + fb)               MFMA K=224
//  4) xp16[d][start+t] = dec16[gather] @ Wih^T + bih     MFMA K=128, per class
//  5) GRU scan: 128 thr (2 waves) per (class,dir); thread g owns rows
//     {g,g+128,g+256}. h broadcast: ONE ds_read_b32/lane + 64 v_readlane.
//     v6: amdgpu_waves_per_eu(1,1) forces the allocator to the full arch
//     VGPR budget — v5 spilled the 192 weight regs (VGPR_Count=136) because
//     the occupancy heuristic targeted multi-wave residency we don't need.
//  6) out[n] = sigmoid(dot(outY[n,:256], out_W) + out_b)

typedef _Float16 half2_t __attribute__((ext_vector_type(2)));
typedef _Float16 half8_t __attribute__((ext_vector_type(8)));
typedef float f32x4 __attribute__((ext_vector_type(4)));

// LDS-only barrier: __syncthreads() drains vmcnt (in-flight global ops);
// cross-thread data here flows only through LDS, lgkmcnt(0) suffices.
__device__ __forceinline__ void lds_barrier() {
    asm volatile("s_waitcnt lgkmcnt(0)\n\ts_barrier" ::: "memory");
}

__device__ __forceinline__ half8_t cvt8(float4 f0, float4 f1) {
    return half8_t{(_Float16)f0.x, (_Float16)f0.y, (_Float16)f0.z, (_Float16)f0.w,
                   (_Float16)f1.x, (_Float16)f1.y, (_Float16)f1.z, (_Float16)f1.w};
}

// ---------------- 1. concat extras (f16) ----------------
__global__ __launch_bounds__(256) void concat_kernel(
    const float* __restrict__ score, const float* __restrict__ box,
    const float* __restrict__ orig, _Float16* __restrict__ allf, int N)
{
    int idx = blockIdx.x * 256 + threadIdx.x;
    int total = N * 96;
    if (idx >= total) return;
    int n = idx / 96, j = idx - n * 96;
    float v;
    if (j < 32)      v = score[(size_t)n * 32 + j];
    else if (j < 64) v = box  [(size_t)n * 32 + j - 32];
    else             v = orig [(size_t)n * 32 + j - 64];
    allf[(size_t)n * 224 + 128 + j] = (_Float16)v;
}

// ---------------- MFMA GEMM: C(N x 128) = act(A(N x K) @ B(128 x K)^T + bias) ----------------
// 256 thr = 4 waves; tile 64 rows x 128 cols; wave = 1 row-tile(16) x 8 col-tiles.
// K-chunk 32. LDS staged in MFMA fragment order (lane-contiguous 16B slots):
//   A slot u = rt*64 + q*16 + m  <- A[n0+rt*16+m][kc*32 + q*8 .. +7]
//   B slot u = ct*64 + q*16 + n  <- B[ct*16+n]  [kc*32 + q*8 .. +7]
// Frag layouts (m89-verified): A/B lane = idx&15 + 16*(k/8); C/D col=lane&15,
// row = 4*(lane>>4) + reg.
template<bool A_F16>
__global__ __launch_bounds__(256) void mfma_gemm_kernel(
    const void* __restrict__ Av, int lda,
    const float* __restrict__ B, int ldb,       // 128 x ldb f32 (ldb >= K)
    const float* __restrict__ bias,
    _Float16* __restrict__ Cc, int ldc,
    int Nrows, int K, int do_relu)
{
    __shared__ __align__(16) _Float16 Asl[256 * 8];   // 4 KB
    __shared__ __align__(16) _Float16 Bsl[512 * 8];   // 8 KB
    const int tid = threadIdx.x;
    const int wave = tid >> 6, lane = tid & 63;
    const int n0 = blockIdx.x * 64;

    // A staging: slot = tid
    const int a_rt = tid >> 6, a_q = (tid >> 4) & 3, a_m = tid & 15;
    int arow = n0 + a_rt * 16 + a_m; if (arow > Nrows - 1) arow = Nrows - 1;
    // B staging: slots tid and tid+256
    const int b_q = (tid >> 4) & 3, b_n = tid & 15;
    const int bcol0 = (tid >> 6) * 16 + b_n;          // ct 0..3
    const int bcol1 = bcol0 + 64;                     // ct 4..7

    f32x4 acc[8] = {};
    half8_t a_st, b_st0, b_st1;

    auto load_chunk = [&](int kc) {
        int k = kc * 32;
        if constexpr (A_F16) {
            const _Float16* A = (const _Float16*)Av;
            a_st = *(const half8_t*)(A + (size_t)arow * lda + k + a_q * 8);
        } else {
            const float* A = (const float*)Av;
            const float4* p = (const float4*)(A + (size_t)arow * lda + k + a_q * 8);
            a_st = cvt8(p[0], p[1]);
        }
        const float4* p0 = (const float4*)(B + (size_t)bcol0 * ldb + k + b_q * 8);
        const float4* p1 = (const float4*)(B + (size_t)bcol1 * ldb + k + b_q * 8);
        b_st0 = cvt8(p0[0], p0[1]);
        b_st1 = cvt8(p1[0], p1[1]);
    };

    load_chunk(0);
    const int nkc = K >> 5;
    for (int kc = 0; kc < nkc; kc++) {
        lds_barrier();                       // prev compute's LDS reads done
        *(half8_t*)(Asl + tid * 8) = a_st;
        *(half8_t*)(Bsl + tid * 8) = b_st0;
        *(half8_t*)(Bsl + (tid + 256) * 8) = b_st1;
        lds_barrier();
        if (kc + 1 < nkc) load_chunk(kc + 1);   // prefetch under MFMA
        half8_t af = *(const half8_t*)(Asl + (wave * 64 + lane) * 8);
        #pragma unroll
        for (int ct = 0; ct < 8; ct++) {
            half8_t bf = *(const half8_t*)(Bsl + (ct * 64 + lane) * 8);
            acc[ct] = __builtin_amdgcn_mfma_f32_16x16x32_f16(af, bf, acc[ct], 0, 0, 0);
        }
    }

    const int crow = n0 + wave * 16 + (lane >> 4) * 4;
    const int ccol = lane & 15;
    #pragma unroll
    for (int ct = 0; ct < 8; ct++) {
        int col = ct * 16 + ccol;
        float bv = bias[col];
        #pragma unroll
        for (int reg = 0; reg < 4; reg++) {
            int row = crow + reg;
            if (row >= Nrows) continue;
            float v = acc[ct][reg] + bv;
            if (do_relu) v = v > 0.f ? v : 0.f;
            Cc[(size_t)row * ldc + col] = (_Float16)v;
        }
    }
}

// ---------------- 4. Xp per-class MFMA GEMM (K=128) with direction gather ----------------
__global__ __launch_bounds__(256) void mfma_xp_kernel(
    const _Float16* __restrict__ dec, // N x 128 f16
    const float* __restrict__ Wih,    // C x 2 x 384 x 128 f32
    const float* __restrict__ bih,    // C x 2 x 384 f32
    const int* __restrict__ ucl,
    _Float16* __restrict__ xp,        // 2 x N x 384 f16
    int N)
{
    const int c = blockIdx.x;
    const int tile = blockIdx.y;
    const int d = blockIdx.z / 3, mt = blockIdx.z % 3;
    const int start = ucl[c];
    const int len = ucl[c + 1] - start;
    const int t0 = tile * 64;
    if (t0 >= len) return;

    __shared__ __align__(16) _Float16 Asl[256 * 8];
    __shared__ __align__(16) _Float16 Bsl[512 * 8];
    const int tid = threadIdx.x;
    const int wave = tid >> 6, lane = tid & 63;

    const int a_rt = tid >> 6, a_q = (tid >> 4) & 3, a_m = tid & 15;
    int t = t0 + a_rt * 16 + a_m; if (t > len - 1) t = len - 1;
    const int srow = start + (d ? (len - 1 - t) : t);

    const float* Bb = Wih + ((size_t)(c * 2 + d) * 384 + mt * 128) * 128;
    const int b_q = (tid >> 4) & 3, b_n = tid & 15;
    const int bcol0 = (tid >> 6) * 16 + b_n;
    const int bcol1 = bcol0 + 64;

    f32x4 acc[8] = {};
    half8_t a_st, b_st0, b_st1;

    auto load_chunk = [&](int kc) {
        int k = kc * 32;
        a_st = *(const half8_t*)(dec + (size_t)srow * 128 + k + a_q * 8);
        const float4* p0 = (const float4*)(Bb + (size_t)bcol0 * 128 + k + b_q * 8);
        const float4* p1 = (const float4*)(Bb + (size_t)bcol1 * 128 + k + b_q * 8);
        b_st0 = cvt8(p0[0], p0[1]);
        b_st1 = cvt8(p1[0], p1[1]);
    };

    load_chunk(0);
    for (int kc = 0; kc < 4; kc++) {
        lds_barrier();
        *(half8_t*)(Asl + tid * 8) = a_st;
        *(half8_t*)(Bsl + tid * 8) = b_st0;
        *(half8_t*)(Bsl + (tid + 256) * 8) = b_st1;
        lds_barrier();
        if (kc + 1 < 4) load_chunk(kc + 1);
        half8_t af = *(const half8_t*)(Asl + (wave * 64 + lane) * 8);
        #pragma unroll
        for (int ct = 0; ct < 8; ct++) {
            half8_t bf = *(const half8_t*)(Bsl + (ct * 64 + lane) * 8);
            acc[ct] = __builtin_amdgcn_mfma_f32_16x16x32_f16(af, bf, acc[ct], 0, 0, 0);
        }
    }

    const float* bias = bih + (size_t)(c * 2 + d) * 384 + mt * 128;
    const int trow = t0 + wave * 16 + (lane >> 4) * 4;
    const int ccol = lane & 15;
    #pragma unroll
    for (int ct = 0; ct < 8; ct++) {
        int col = ct * 16 + ccol;
        float bv = bias[col];
        #pragma unroll
        for (int reg = 0; reg < 4; reg++) {
            int tt = trow + reg;
            if (tt >= len) continue;
            float v = acc[ct][reg] + bv;
            xp[((size_t)d * N + start + tt) * 384 + mt * 128 + col] = (_Float16)v;
        }
    }
}

// ---------------- 5. GRU scan: 2 waves, readlane broadcast ----------------
// One block per (class,dir), 128 threads; thread g owns gate rows
// {g, g+128, g+256}. Weights: 192 half2 VGPRs/thread (consecutive-pair
// packing w[i] = (W[row][2i], W[row][2i+1])).
// amdgpu_waves_per_eu(1,1): allocator must assume single-wave residency ->
// full arch-VGPR budget -> the 192 weight regs stay resident (v5's
// occupancy-heuristic build spilled them at VGPR_Count=136).
// Serial chain per substep: ds_read_b32 (lane l -> pair h[2l],h[2l+1])
// -> lgkmcnt(0) -> 64 readlane + 192 dot2 (6 acc chains) -> activations
// -> ds_write_b16 -> lds_barrier. x prefetched 1 step ahead from global.
__global__ __launch_bounds__(128, 1)
__attribute__((amdgpu_waves_per_eu(1, 1)))
void gru_kernel(
    const _Float16* __restrict__ xp,  // 2 x N x 384 f16
    const float* __restrict__ Whh,    // C x 2 x 384 x 128
    const float* __restrict__ bhh,    // C x 2 x 384
    const int* __restrict__ ucl,
    float* __restrict__ outY,         // N x 256 f32
    int N)
{
    const int c = blockIdx.x, d = blockIdx.y;
    const int start = ucl[c];
    const int len = ucl[c + 1] - start;
    const int g = threadIdx.x;        // 0..127
    const int l = g & 63;             // lane

    const float* wbase = Whh + (size_t)(c * 2 + d) * 384 * 128;
    half2_t w0[64], w1[64], w2[64];
    {
        const float2* r0 = (const float2*)(wbase + (size_t)g * 128);
        const float2* r1 = (const float2*)(wbase + (size_t)(g + 128) * 128);
        const float2* r2 = (const float2*)(wbase + (size_t)(g + 256) * 128);
        #pragma unroll
        for (int i = 0; i < 64; i++) {
            float2 a = r0[i];
            w0[i] = half2_t{(_Float16)a.x, (_Float16)a.y};
        }
        #pragma unroll
        for (int i = 0; i < 64; i++) {
            float2 a = r1[i];
            w1[i] = half2_t{(_Float16)a.x, (_Float16)a.y};
        }
        #pragma unroll
        for (int i = 0; i < 64; i++) {
            float2 a = r2[i];
            w2[i] = half2_t{(_Float16)a.x, (_Float16)a.y};
        }
    }
    const float* bb = bhh + (size_t)(c * 2 + d) * 384;
    const float bh0 = bb[g], bh1 = bb[g + 128], bh2 = bb[g + 256];

    __shared__ __align__(4) _Float16 hbuf[2][128];    // 512 B double buffer
    hbuf[0][g] = (_Float16)0.f;

    const _Float16* xpb = xp + ((size_t)d * N + start) * 384;
    float* outb = outY + (size_t)start * 256 + d * 128;

    float x0 = (float)xpb[g], x1 = (float)xpb[128 + g], x2 = (float)xpb[256 + g];
    float hcur = 0.f;
    lds_barrier();

    for (int t = 0; t < len; t++) {
        // h pair for this lane: (h[2l], h[2l+1]) — one b32, conflict-free,
        // identical content in both waves.
        int hvi = ((const int*)hbuf[t & 1])[l];

        // prefetch next step's x under the dot loop (off-chain)
        int tn = (t + 1 < len) ? (t + 1) : t;
        const _Float16* xt = xpb + (size_t)tn * 384;
        float p0 = (float)xt[g], p1 = (float)xt[128 + g], p2 = (float)xt[256 + g];

        float a0 = bh0, a1 = bh1, a2 = bh2;
        float b0 = 0.f, b1 = 0.f, b2 = 0.f;
        #pragma unroll
        for (int i = 0; i < 32; i++) {
            int hbL = __builtin_amdgcn_readlane(hvi, i);
            int hbH = __builtin_amdgcn_readlane(hvi, i + 32);
            half2_t hL = __builtin_bit_cast(half2_t, hbL);
            half2_t hH = __builtin_bit_cast(half2_t, hbH);
            a0 = __builtin_amdgcn_fdot2(w0[i],      hL, a0, false);
            b0 = __builtin_amdgcn_fdot2(w0[i + 32], hH, b0, false);
            a1 = __builtin_amdgcn_fdot2(w1[i],      hL, a1, false);
            b1 = __builtin_amdgcn_fdot2(w1[i + 32], hH, b1, false);
            a2 = __builtin_amdgcn_fdot2(w2[i],      hL, a2, false);
            b2 = __builtin_amdgcn_fdot2(w2[i + 32], hH, b2, false);
        }
        a0 += b0; a1 += b1; a2 += b2;

        float r = __fdividef(1.f, 1.f + __expf(-(x0 + a0)));
        float z = __fdividef(1.f, 1.f + __expf(-(x1 + a1)));
        float pre = x2 + r * a2;
        float n = 1.f - __fdividef(2.f, __expf(2.f * pre) + 1.f);
        float hnew = (1.f - z) * n + z * hcur;

        hbuf[(t + 1) & 1][g] = (_Float16)hnew;
        hcur = hnew;

        int tt = d ? (len - 1 - t) : t;
        outb[(size_t)tt * 256 + g] = hnew;

        x0 = p0; x1 = p1; x2 = p2;
        lds_barrier();
    }
}

// ---------------- 6. head: sigmoid(dot(outY[n], out_W) + b) ----------------
__global__ __launch_bounds__(256) void final_kernel(
    const float* __restrict__ outY,   // N x 256
    const float* __restrict__ outW,   // 256
    const float* __restrict__ outb,   // 1
    float* __restrict__ out, int N)
{
    __shared__ __align__(16) float wsh[256];
    wsh[threadIdx.x] = outW[threadIdx.x];
    __syncthreads();
    const int lane = threadIdx.x & 63;
    const int wave = (blockIdx.x * 256 + threadIdx.x) >> 6;
    const int nw = gridDim.x * 4;
    float4 w4 = *(const float4*)&wsh[lane * 4];
    float b = outb[0];
    for (int n = wave; n < N; n += nw) {
        float4 y = *(const float4*)(outY + (size_t)n * 256 + lane * 4);
        float p = y.x * w4.x + y.y * w4.y + y.z * w4.z + y.w * w4.w;
        #pragma unroll
        for (int off = 32; off > 0; off >>= 1) p += __shfl_down(p, off);
        if (lane == 0) out[n] = 1.f / (1.f + __expf(-(p + b)));
    }
}

extern "C" void kernel_launch(void* const* d_in, const int* in_sizes, int n_in,
                              void* d_out, int out_size, void* d_ws, size_t ws_size,
                              hipStream_t stream)
{
    const float* acbf  = (const float*)d_in[3];
    const float* score = (const float*)d_in[4];
    const float* box   = (const float*)d_in[5];
    const float* orig  = (const float*)d_in[6];
    const int*   ucl   = (const int*)d_in[8];
    const float* aW  = (const float*)d_in[9];
    const float* ab  = (const float*)d_in[10];
    const float* fW  = (const float*)d_in[11];
    const float* fb  = (const float*)d_in[12];
    const float* Wih = (const float*)d_in[13];
    const float* Whh = (const float*)d_in[14];
    const float* bih = (const float*)d_in[15];
    const float* bhh = (const float*)d_in[16];
    const float* oW  = (const float*)d_in[17];
    const float* ob  = (const float*)d_in[18];
    float* out = (float*)d_out;

    const int N = in_sizes[3] / 1024;   // 20640
    const int C = in_sizes[7];          // 80

    // workspace: allf16 N*224 | dec16 N*128 | xp16 2*N*384 | outY f32 N*256  (~67 MB)
    _Float16* allf16 = (_Float16*)d_ws;
    _Float16* dec16  = allf16 + (size_t)N * 224;
    _Float16* xp16   = dec16 + (size_t)N * 128;
    float*    outY   = (float*)(xp16 + (size_t)2 * N * 384);

    dim3 blk(256);
    const int rowblocks = (N + 63) / 64;
    concat_kernel<<<dim3((N * 96 + 255) / 256), blk, 0, stream>>>(score, box, orig, allf16, N);
    mfma_gemm_kernel<false><<<dim3(rowblocks), blk, 0, stream>>>(
        (const void*)acbf, 1024, aW, 1024, ab, allf16, 224, N, 1024, 1);
    mfma_gemm_kernel<true><<<dim3(rowblocks), blk, 0, stream>>>(
        (const void*)allf16, 224, fW, 224, fb, dec16, 128, N, 224, 1);
    mfma_xp_kernel<<<dim3(C, 7, 6), blk, 0, stream>>>(dec16, Wih, bih, ucl, xp16, N);
    gru_kernel<<<dim3(C, 2), dim3(128), 0, stream>>>(xp16, Whh, bhh, ucl, outY, N);
    final_kernel<<<dim3(160), blk, 0, stream>>>(outY, oW, ob, out, N);
}

// Round 7
// 627.369 us; speedup vs baseline: 1.4829x; 1.0024x over previous
//
#include <hip/hip_runtime.h>
#include <hip/hip_bf16.h>
#include <cstdint>

// Encoder_Decoder: C=80 classes, H=128, N=sum(lengths)=20640, L_max=416.
// Phases (all dense GEMMs f16 MFMA, fp32 accumulate):
//  1) concat extras (f16) into allf16[:,128:224]
//  2) allf16[:,:128] = relu(acbf @ appear_W^T + ab)      MFMA K=1024
//  3) dec16 = relu(allf16 @ feat_W^T + fb)               MFMA K=224
//  4) xp16[d][start+t] = dec16[gather] @ Wih^T + bih     MFMA K=128, per class
//  5) GRU scan: 128 thr (2 waves) per (class,dir); thread g owns rows
//     {g,g+128,g+256}. h broadcast: ONE ds_read_b32/lane + 64 v_readlane.
//     v7: the 192 weight half2s are NAMED registers (macro-generated) —
//     the array form was SROA/regalloc-demoted in v5/v6 (VGPR_Count=136,
//     spill reloads on the chain). 192 named + ~40 temps = ~230 < 256
//     VALU-addressable cap, so residency is feasible (v4's named variant
//     failed only because 384 exceeded the cap).
//  6) out[n] = sigmoid(dot(outY[n,:256], out_W) + out_b)

typedef _Float16 half2_t __attribute__((ext_vector_type(2)));
typedef _Float16 half8_t __attribute__((ext_vector_type(8)));
typedef float f32x4 __attribute__((ext_vector_type(4)));

// LDS-only barrier: __syncthreads() drains vmcnt (in-flight global ops);
// cross-thread data here flows only through LDS, lgkmcnt(0) suffices.
__device__ __forceinline__ void lds_barrier() {
    asm volatile("s_waitcnt lgkmcnt(0)\n\ts_barrier" ::: "memory");
}

__device__ __forceinline__ half8_t cvt8(float4 f0, float4 f1) {
    return half8_t{(_Float16)f0.x, (_Float16)f0.y, (_Float16)f0.z, (_Float16)f0.w,
                   (_Float16)f1.x, (_Float16)f1.y, (_Float16)f1.z, (_Float16)f1.w};
}

// ---------------- 1. concat extras (f16) ----------------
__global__ __launch_bounds__(256) void concat_kernel(
    const float* __restrict__ score, const float* __restrict__ box,
    const float* __restrict__ orig, _Float16* __restrict__ allf, int N)
{
    int idx = blockIdx.x * 256 + threadIdx.x;
    int total = N * 96;
    if (idx >= total) return;
    int n = idx / 96, j = idx - n * 96;
    float v;
    if (j < 32)      v = score[(size_t)n * 32 + j];
    else if (j < 64) v = box  [(size_t)n * 32 + j - 32];
    else             v = orig [(size_t)n * 32 + j - 64];
    allf[(size_t)n * 224 + 128 + j] = (_Float16)v;
}

// ---------------- MFMA GEMM: C(N x 128) = act(A(N x K) @ B(128 x K)^T + bias) ----------------
// 256 thr = 4 waves; tile 64 rows x 128 cols; wave = 1 row-tile(16) x 8 col-tiles.
// K-chunk 32. LDS staged in MFMA fragment order (lane-contiguous 16B slots):
//   A slot u = rt*64 + q*16 + m  <- A[n0+rt*16+m][kc*32 + q*8 .. +7]
//   B slot u = ct*64 + q*16 + n  <- B[ct*16+n]  [kc*32 + q*8 .. +7]
// Frag layouts (m89-verified): A/B lane = idx&15 + 16*(k/8); C/D col=lane&15,
// row = 4*(lane>>4) + reg.
template<bool A_F16>
__global__ __launch_bounds__(256) void mfma_gemm_kernel(
    const void* __restrict__ Av, int lda,
    const float* __restrict__ B, int ldb,       // 128 x ldb f32 (ldb >= K)
    const float* __restrict__ bias,
    _Float16* __restrict__ Cc, int ldc,
    int Nrows, int K, int do_relu)
{
    __shared__ __align__(16) _Float16 Asl[256 * 8];   // 4 KB
    __shared__ __align__(16) _Float16 Bsl[512 * 8];   // 8 KB
    const int tid = threadIdx.x;
    const int wave = tid >> 6, lane = tid & 63;
    const int n0 = blockIdx.x * 64;

    // A staging: slot = tid
    const int a_rt = tid >> 6, a_q = (tid >> 4) & 3, a_m = tid & 15;
    int arow = n0 + a_rt * 16 + a_m; if (arow > Nrows - 1) arow = Nrows - 1;
    // B staging: slots tid and tid+256
    const int b_q = (tid >> 4) & 3, b_n = tid & 15;
    const int bcol0 = (tid >> 6) * 16 + b_n;          // ct 0..3
    const int bcol1 = bcol0 + 64;                     // ct 4..7

    f32x4 acc[8] = {};
    half8_t a_st, b_st0, b_st1;

    auto load_chunk = [&](int kc) {
        int k = kc * 32;
        if constexpr (A_F16) {
            const _Float16* A = (const _Float16*)Av;
            a_st = *(const half8_t*)(A + (size_t)arow * lda + k + a_q * 8);
        } else {
            const float* A = (const float*)Av;
            const float4* p = (const float4*)(A + (size_t)arow * lda + k + a_q * 8);
            a_st = cvt8(p[0], p[1]);
        }
        const float4* p0 = (const float4*)(B + (size_t)bcol0 * ldb + k + b_q * 8);
        const float4* p1 = (const float4*)(B + (size_t)bcol1 * ldb + k + b_q * 8);
        b_st0 = cvt8(p0[0], p0[1]);
        b_st1 = cvt8(p1[0], p1[1]);
    };

    load_chunk(0);
    const int nkc = K >> 5;
    for (int kc = 0; kc < nkc; kc++) {
        lds_barrier();                       // prev compute's LDS reads done
        *(half8_t*)(Asl + tid * 8) = a_st;
        *(half8_t*)(Bsl + tid * 8) = b_st0;
        *(half8_t*)(Bsl + (tid + 256) * 8) = b_st1;
        lds_barrier();
        if (kc + 1 < nkc) load_chunk(kc + 1);   // prefetch under MFMA
        half8_t af = *(const half8_t*)(Asl + (wave * 64 + lane) * 8);
        #pragma unroll
        for (int ct = 0; ct < 8; ct++) {
            half8_t bf = *(const half8_t*)(Bsl + (ct * 64 + lane) * 8);
            acc[ct] = __builtin_amdgcn_mfma_f32_16x16x32_f16(af, bf, acc[ct], 0, 0, 0);
        }
    }

    const int crow = n0 + wave * 16 + (lane >> 4) * 4;
    const int ccol = lane & 15;
    #pragma unroll
    for (int ct = 0; ct < 8; ct++) {
        int col = ct * 16 + ccol;
        float bv = bias[col];
        #pragma unroll
        for (int reg = 0; reg < 4; reg++) {
            int row = crow + reg;
            if (row >= Nrows) continue;
            float v = acc[ct][reg] + bv;
            if (do_relu) v = v > 0.f ? v : 0.f;
            Cc[(size_t)row * ldc + col] = (_Float16)v;
        }
    }
}

// ---------------- 4. Xp per-class MFMA GEMM (K=128) with direction gather ----------------
__global__ __launch_bounds__(256) void mfma_xp_kernel(
    const _Float16* __restrict__ dec, // N x 128 f16
    const float* __restrict__ Wih,    // C x 2 x 384 x 128 f32
    const float* __restrict__ bih,    // C x 2 x 384 f32
    const int* __restrict__ ucl,
    _Float16* __restrict__ xp,        // 2 x N x 384 f16
    int N)
{
    const int c = blockIdx.x;
    const int tile = blockIdx.y;
    const int d = blockIdx.z / 3, mt = blockIdx.z % 3;
    const int start = ucl[c];
    const int len = ucl[c + 1] - start;
    const int t0 = tile * 64;
    if (t0 >= len) return;

    __shared__ __align__(16) _Float16 Asl[256 * 8];
    __shared__ __align__(16) _Float16 Bsl[512 * 8];
    const int tid = threadIdx.x;
    const int wave = tid >> 6, lane = tid & 63;

    const int a_rt = tid >> 6, a_q = (tid >> 4) & 3, a_m = tid & 15;
    int t = t0 + a_rt * 16 + a_m; if (t > len - 1) t = len - 1;
    const int srow = start + (d ? (len - 1 - t) : t);

    const float* Bb = Wih + ((size_t)(c * 2 + d) * 384 + mt * 128) * 128;
    const int b_q = (tid >> 4) & 3, b_n = tid & 15;
    const int bcol0 = (tid >> 6) * 16 + b_n;
    const int bcol1 = bcol0 + 64;

    f32x4 acc[8] = {};
    half8_t a_st, b_st0, b_st1;

    auto load_chunk = [&](int kc) {
        int k = kc * 32;
        a_st = *(const half8_t*)(dec + (size_t)srow * 128 + k + a_q * 8);
        const float4* p0 = (const float4*)(Bb + (size_t)bcol0 * 128 + k + b_q * 8);
        const float4* p1 = (const float4*)(Bb + (size_t)bcol1 * 128 + k + b_q * 8);
        b_st0 = cvt8(p0[0], p0[1]);
        b_st1 = cvt8(p1[0], p1[1]);
    };

    load_chunk(0);
    for (int kc = 0; kc < 4; kc++) {
        lds_barrier();
        *(half8_t*)(Asl + tid * 8) = a_st;
        *(half8_t*)(Bsl + tid * 8) = b_st0;
        *(half8_t*)(Bsl + (tid + 256) * 8) = b_st1;
        lds_barrier();
        if (kc + 1 < 4) load_chunk(kc + 1);
        half8_t af = *(const half8_t*)(Asl + (wave * 64 + lane) * 8);
        #pragma unroll
        for (int ct = 0; ct < 8; ct++) {
            half8_t bf = *(const half8_t*)(Bsl + (ct * 64 + lane) * 8);
            acc[ct] = __builtin_amdgcn_mfma_f32_16x16x32_f16(af, bf, acc[ct], 0, 0, 0);
        }
    }

    const float* bias = bih + (size_t)(c * 2 + d) * 384 + mt * 128;
    const int trow = t0 + wave * 16 + (lane >> 4) * 4;
    const int ccol = lane & 15;
    #pragma unroll
    for (int ct = 0; ct < 8; ct++) {
        int col = ct * 16 + ccol;
        float bv = bias[col];
        #pragma unroll
        for (int reg = 0; reg < 4; reg++) {
            int tt = trow + reg;
            if (tt >= len) continue;
            float v = acc[ct][reg] + bv;
            xp[((size_t)d * N + start + tt) * 384 + mt * 128 + col] = (_Float16)v;
        }
    }
}

// ---------------- 5. GRU scan: 2 waves, readlane broadcast, named weights ----------------
// One block per (class,dir), 128 threads; thread g owns gate rows
// {g, g+128, g+256}. Weight element i (0..63): w{p}_i = (W[row_p][2i],
// W[row_p][2i+1]) — matches the h-pair (h[2i], h[2i+1]) that readlane(hvi,i)
// broadcasts from lane i. All 192 weights are individually named half2
// registers; the dot chain is fully macro-expanded (static access only).
// Serial chain per substep: ds_read_b32 -> lgkmcnt(0) -> 64 readlane +
// 192 dot2 (6 acc chains) -> activations -> ds_write_b16 -> lds_barrier.
#define RPT_0_31(M)  M(0) M(1) M(2) M(3) M(4) M(5) M(6) M(7) \
                     M(8) M(9) M(10) M(11) M(12) M(13) M(14) M(15) \
                     M(16) M(17) M(18) M(19) M(20) M(21) M(22) M(23) \
                     M(24) M(25) M(26) M(27) M(28) M(29) M(30) M(31)
#define RPT_32_63(M) M(32) M(33) M(34) M(35) M(36) M(37) M(38) M(39) \
                     M(40) M(41) M(42) M(43) M(44) M(45) M(46) M(47) \
                     M(48) M(49) M(50) M(51) M(52) M(53) M(54) M(55) \
                     M(56) M(57) M(58) M(59) M(60) M(61) M(62) M(63)

#define DECLW(i) half2_t w0_##i, w1_##i, w2_##i;

#define LOADW(i)                                                              \
    {                                                                         \
        float2 f0 = r0[i], f1 = r1[i], f2 = r2[i];                            \
        w0_##i = half2_t{(_Float16)f0.x, (_Float16)f0.y};                     \
        w1_##i = half2_t{(_Float16)f1.x, (_Float16)f1.y};                     \
        w2_##i = half2_t{(_Float16)f2.x, (_Float16)f2.y};                     \
    }

#define DOTA(i)                                                               \
    {                                                                         \
        int hb = __builtin_amdgcn_readlane(hvi, i);                           \
        half2_t h2 = __builtin_bit_cast(half2_t, hb);                         \
        a0 = __builtin_amdgcn_fdot2(w0_##i, h2, a0, false);                   \
        a1 = __builtin_amdgcn_fdot2(w1_##i, h2, a1, false);                   \
        a2 = __builtin_amdgcn_fdot2(w2_##i, h2, a2, false);                   \
    }
#define DOTB(i)                                                               \
    {                                                                         \
        int hb = __builtin_amdgcn_readlane(hvi, i);                           \
        half2_t h2 = __builtin_bit_cast(half2_t, hb);                         \
        b0 = __builtin_amdgcn_fdot2(w0_##i, h2, b0, false);                   \
        b1 = __builtin_amdgcn_fdot2(w1_##i, h2, b1, false);                   \
        b2 = __builtin_amdgcn_fdot2(w2_##i, h2, b2, false);                   \
    }

__global__ __launch_bounds__(128, 1)
__attribute__((amdgpu_waves_per_eu(1, 1)))
void gru_kernel(
    const _Float16* __restrict__ xp,  // 2 x N x 384 f16
    const float* __restrict__ Whh,    // C x 2 x 384 x 128
    const float* __restrict__ bhh,    // C x 2 x 384
    const int* __restrict__ ucl,
    float* __restrict__ outY,         // N x 256 f32
    int N)
{
    const int c = blockIdx.x, d = blockIdx.y;
    const int start = ucl[c];
    const int len = ucl[c + 1] - start;
    const int g = threadIdx.x;        // 0..127
    const int l = g & 63;             // lane

    const float* wbase = Whh + (size_t)(c * 2 + d) * 384 * 128;
    const float2* r0 = (const float2*)(wbase + (size_t)g * 128);
    const float2* r1 = (const float2*)(wbase + (size_t)(g + 128) * 128);
    const float2* r2 = (const float2*)(wbase + (size_t)(g + 256) * 128);

    RPT_0_31(DECLW) RPT_32_63(DECLW)
    RPT_0_31(LOADW) RPT_32_63(LOADW)

    const float* bb = bhh + (size_t)(c * 2 + d) * 384;
    const float bh0 = bb[g], bh1 = bb[g + 128], bh2 = bb[g + 256];

    __shared__ __align__(4) _Float16 hbuf[2][128];    // 512 B double buffer
    hbuf[0][g] = (_Float16)0.f;

    const _Float16* xpb = xp + ((size_t)d * N + start) * 384;
    float* outb = outY + (size_t)start * 256 + d * 128;

    float x0 = (float)xpb[g], x1 = (float)xpb[128 + g], x2 = (float)xpb[256 + g];
    float hcur = 0.f;
    lds_barrier();

    for (int t = 0; t < len; t++) {
        // h pair for this lane: (h[2l], h[2l+1]) — one b32, conflict-free,
        // identical content in both waves.
        int hvi = ((const int*)hbuf[t & 1])[l];

        // prefetch next step's x under the dot loop (off-chain)
        int tn = (t + 1 < len) ? (t + 1) : t;
        const _Float16* xt = xpb + (size_t)tn * 384;
        float p0 = (float)xt[g], p1 = (float)xt[128 + g], p2 = (float)xt[256 + g];

        float a0 = bh0, a1 = bh1, a2 = bh2;
        float b0 = 0.f, b1 = 0.f, b2 = 0.f;
        RPT_0_31(DOTA)
        RPT_32_63(DOTB)
        a0 += b0; a1 += b1; a2 += b2;

        float r = __fdividef(1.f, 1.f + __expf(-(x0 + a0)));
        float z = __fdividef(1.f, 1.f + __expf(-(x1 + a1)));
        float pre = x2 + r * a2;
        float n = 1.f - __fdividef(2.f, __expf(2.f * pre) + 1.f);
        float hnew = (1.f - z) * n + z * hcur;

        hbuf[(t + 1) & 1][g] = (_Float16)hnew;
        hcur = hnew;

        int tt = d ? (len - 1 - t) : t;
        outb[(size_t)tt * 256 + g] = hnew;

        x0 = p0; x1 = p1; x2 = p2;
        lds_barrier();
    }
}

// ---------------- 6. head: sigmoid(dot(outY[n], out_W) + b) ----------------
__global__ __launch_bounds__(256) void final_kernel(
    const float* __restrict__ outY,   // N x 256
    const float* __restrict__ outW,   // 256
    const float* __restrict__ outb,   // 1
    float* __restrict__ out, int N)
{
    __shared__ __align__(16) float wsh[256];
    wsh[threadIdx.x] = outW[threadIdx.x];
    __syncthreads();
    const int lane = threadIdx.x & 63;
    const int wave = (blockIdx.x * 256 + threadIdx.x) >> 6;
    const int nw = gridDim.x * 4;
    float4 w4 = *(const float4*)&wsh[lane * 4];
    float b = outb[0];
    for (int n = wave; n < N; n += nw) {
        float4 y = *(const float4*)(outY + (size_t)n * 256 + lane * 4);
        float p = y.x * w4.x + y.y * w4.y + y.z * w4.z + y.w * w4.w;
        #pragma unroll
        for (int off = 32; off > 0; off >>= 1) p += __shfl_down(p, off);
        if (lane == 0) out[n] = 1.f / (1.f + __expf(-(p + b)));
    }
}

extern "C" void kernel_launch(void* const* d_in, const int* in_sizes, int n_in,
                              void* d_out, int out_size, void* d_ws, size_t ws_size,
                              hipStream_t stream)
{
    const float* acbf  = (const float*)d_in[3];
    const float* score = (const float*)d_in[4];
    const float* box   = (const float*)d_in[5];
    const float* orig  = (const float*)d_in[6];
    const int*   ucl   = (const int*)d_in[8];
    const float* aW  = (const float*)d_in[9];
    const float* ab  = (const float*)d_in[10];
    const float* fW  = (const float*)d_in[11];
    const float* fb  = (const float*)d_in[12];
    const float* Wih = (const float*)d_in[13];
    const float* Whh = (const float*)d_in[14];
    const float* bih = (const float*)d_in[15];
    const float* bhh = (const float*)d_in[16];
    const float* oW  = (const float*)d_in[17];
    const float* ob  = (const float*)d_in[18];
    float* out = (float*)d_out;

    const int N = in_sizes[3] / 1024;   // 20640
    const int C = in_sizes[7];          // 80

    // workspace: allf16 N*224 | dec16 N*128 | xp16 2*N*384 | outY f32 N*256  (~67 MB)
    _Float16* allf16 = (_Float16*)d_ws;
    _Float16* dec16  = allf16 + (size_t)N * 224;
    _Float16* xp16   = dec16 + (size_t)N * 128;
    float*    outY   = (float*)(xp16 + (size_t)2 * N * 384);

    dim3 blk(256);
    const int rowblocks = (N + 63) / 64;
    concat_kernel<<<dim3((N * 96 + 255) / 256), blk, 0, stream>>>(score, box, orig, allf16, N);
    mfma_gemm_kernel<false><<<dim3(rowblocks), blk, 0, stream>>>(
        (const void*)acbf, 1024, aW, 1024, ab, allf16, 224, N, 1024, 1);
    mfma_gemm_kernel<true><<<dim3(rowblocks), blk, 0, stream>>>(
        (const void*)allf16, 224, fW, 224, fb, dec16, 128, N, 224, 1);
    mfma_xp_kernel<<<dim3(C, 7, 6), blk, 0, stream>>>(dec16, Wih, bih, ucl, xp16, N);
    gru_kernel<<<dim3(C, 2), dim3(128), 0, stream>>>(xp16, Whh, bhh, ucl, outY, N);
    final_kernel<<<dim3(160), blk, 0, stream>>>(outY, oW, ob, out, N);
}